// Round 1
// baseline (2037.503 us; speedup 1.0000x reference)
//
#include <hip/hip_runtime.h>

#define N_NODES 65536
#define N_EDGES 2097152
#define NB      1024
#define FXD     78
#define DIM     32
#define EMBD    128
#define OUTD    128
#define VOCAB   26
#define PLEN    1000
#define KS      8
#define CLEN    121      // EMBD-KS+1
#define NF      32
#define FCX     (NF*CLEN)  // 3872

// ---------------- GIN layer kernels ----------------

// Layer-1 transform: t = x @ w1a ; agg = t (self term).
__global__ __launch_bounds__(256) void k_l1_transform(
    const float* __restrict__ x, const float* __restrict__ w,
    float* __restrict__ t, float* __restrict__ agg)
{
    __shared__ float wS[FXD*DIM];
    for (int i = threadIdx.x; i < FXD*DIM; i += 256) wS[i] = w[i];
    __syncthreads();
    int node = blockIdx.x*256 + threadIdx.x;
    float acc[DIM];
    #pragma unroll
    for (int d=0; d<DIM; ++d) acc[d] = 0.f;
    const float* xr = x + (long)node*FXD;
    for (int j=0; j<FXD; ++j) {
        float xv = xr[j];
        #pragma unroll
        for (int d=0; d<DIM; ++d) acc[d] += xv * wS[j*DIM+d];
    }
    float4* t4 = (float4*)(t + (long)node*DIM);
    float4* a4 = (float4*)(agg + (long)node*DIM);
    #pragma unroll
    for (int q=0; q<DIM/4; ++q) {
        float4 v = make_float4(acc[q*4],acc[q*4+1],acc[q*4+2],acc[q*4+3]);
        t4[q]=v; a4[q]=v;
    }
}

// Layers 2-5 transform: h = BN(z) via scale/shift; t = h @ w ; agg = t.
__global__ __launch_bounds__(256) void k_transform(
    const float* __restrict__ z, const float* __restrict__ ss,
    const float* __restrict__ w,
    float* __restrict__ t, float* __restrict__ agg)
{
    __shared__ float wS[DIM*DIM];
    __shared__ float sS[2*DIM];
    for (int i = threadIdx.x; i < DIM*DIM; i += 256) wS[i] = w[i];
    if (threadIdx.x < 2*DIM) sS[threadIdx.x] = ss[threadIdx.x];
    __syncthreads();
    int node = blockIdx.x*256 + threadIdx.x;
    float h[DIM];
    const float4* z4 = (const float4*)(z + (long)node*DIM);
    #pragma unroll
    for (int q=0; q<DIM/4; ++q) {
        float4 v = z4[q];
        h[q*4+0]=v.x; h[q*4+1]=v.y; h[q*4+2]=v.z; h[q*4+3]=v.w;
    }
    #pragma unroll
    for (int d=0; d<DIM; ++d) h[d] = h[d]*sS[d] + sS[DIM+d];
    float acc[DIM];
    #pragma unroll
    for (int d=0; d<DIM; ++d) acc[d] = 0.f;
    #pragma unroll
    for (int j=0; j<DIM; ++j) {
        float hv = h[j];
        #pragma unroll
        for (int d=0; d<DIM; ++d) acc[d] += hv * wS[j*DIM+d];
    }
    float4* t4 = (float4*)(t + (long)node*DIM);
    float4* a4 = (float4*)(agg + (long)node*DIM);
    #pragma unroll
    for (int q=0; q<DIM/4; ++q) {
        float4 v = make_float4(acc[q*4],acc[q*4+1],acc[q*4+2],acc[q*4+3]);
        t4[q]=v; a4[q]=v;
    }
}

// Edge scatter: agg[dst] += t[src]; 32 lanes per edge (one 128B row each way).
__global__ __launch_bounds__(256) void k_edges(
    const int* __restrict__ ei, const float* __restrict__ t, float* __restrict__ agg)
{
    long g = (long)blockIdx.x*256 + threadIdx.x;
    int e = (int)(g >> 5);
    int c = (int)(g & 31);
    int s = ei[e];
    int d = ei[N_EDGES + e];
    atomicAdd(&agg[(long)d*DIM + c], t[(long)s*DIM + c]);
}

// MLP: u = ReLU(agg + bi); z = ReLU(u @ wo + bo); accumulate channel sums/sumsq.
__global__ __launch_bounds__(256) void k_mlp(
    const float* __restrict__ agg, const float* __restrict__ bi,
    const float* __restrict__ wo, const float* __restrict__ bo,
    float* __restrict__ z, float* __restrict__ stats)
{
    __shared__ float wS[DIM*DIM];
    __shared__ float bS[2*DIM];
    __shared__ float stS[2*DIM];
    for (int i = threadIdx.x; i < DIM*DIM; i += 256) wS[i] = wo[i];
    if (threadIdx.x < DIM) bS[threadIdx.x] = bi[threadIdx.x];
    else if (threadIdx.x < 2*DIM) bS[threadIdx.x] = bo[threadIdx.x - DIM];
    if (threadIdx.x < 2*DIM) stS[threadIdx.x] = 0.f;
    __syncthreads();
    int node = blockIdx.x*256 + threadIdx.x;
    float u[DIM];
    const float4* a4 = (const float4*)(agg + (long)node*DIM);
    #pragma unroll
    for (int q=0; q<DIM/4; ++q) {
        float4 v = a4[q];
        u[q*4+0]=v.x; u[q*4+1]=v.y; u[q*4+2]=v.z; u[q*4+3]=v.w;
    }
    #pragma unroll
    for (int d=0; d<DIM; ++d) u[d] = fmaxf(u[d] + bS[d], 0.f);
    float zz[DIM];
    #pragma unroll
    for (int d=0; d<DIM; ++d) zz[d] = bS[DIM+d];
    #pragma unroll
    for (int j=0; j<DIM; ++j) {
        float uv = u[j];
        #pragma unroll
        for (int d=0; d<DIM; ++d) zz[d] += uv * wS[j*DIM+d];
    }
    #pragma unroll
    for (int d=0; d<DIM; ++d) zz[d] = fmaxf(zz[d], 0.f);
    float4* z4 = (float4*)(z + (long)node*DIM);
    #pragma unroll
    for (int q=0; q<DIM/4; ++q)
        z4[q] = make_float4(zz[q*4],zz[q*4+1],zz[q*4+2],zz[q*4+3]);
    // stats: staggered channel order to avoid same-address LDS serialization
    int lane = threadIdx.x & 63;
    #pragma unroll
    for (int q=0; q<DIM; ++q) {
        int d = (q + lane) & (DIM-1);
        float v = zz[d];
        atomicAdd(&stS[d], v);
        atomicAdd(&stS[DIM+d], v*v);
    }
    __syncthreads();
    if (threadIdx.x < 2*DIM) atomicAdd(&stats[threadIdx.x], stS[threadIdx.x]);
}

__global__ void k_scaleshift(const float* __restrict__ stats,
                             const float* __restrict__ gamma, const float* __restrict__ beta,
                             int layer, float* __restrict__ ss)
{
    int d = threadIdx.x;
    if (d < DIM) {
        float mean = stats[d] * (1.f/N_NODES);
        float var  = stats[DIM+d] * (1.f/N_NODES) - mean*mean;
        float sc = gamma[layer*DIM+d] * rsqrtf(var + 1e-5f);
        ss[d] = sc;
        ss[DIM+d] = beta[layer*DIM+d] - mean*sc;
    }
}

// Global add pool with BN applied: hg[batch[n]] += BN(z[n])
__global__ __launch_bounds__(256) void k_pool(
    const float* __restrict__ z, const float* __restrict__ ss,
    const int* __restrict__ batch, float* __restrict__ hg)
{
    long g = (long)blockIdx.x*256 + threadIdx.x;
    int node = (int)(g >> 5);
    int c = (int)(g & 31);
    int b = batch[node];
    float v = z[(long)node*DIM + c]*ss[c] + ss[DIM+c];
    atomicAdd(&hg[b*DIM + c], v);
}

// xd = ReLU(hg @ w_fcxd + b) -> xc[:, 0:128]
__global__ __launch_bounds__(128) void k_xd(
    const float* __restrict__ hg, const float* __restrict__ w,
    const float* __restrict__ bias, float* __restrict__ xc)
{
    int b = blockIdx.x, n = threadIdx.x;
    __shared__ float hS[DIM];
    if (n < DIM) hS[n] = hg[b*DIM+n];
    __syncthreads();
    float acc = bias[n];
    #pragma unroll
    for (int r=0; r<DIM; ++r) acc += hS[r]*w[r*OUTD+n];
    xc[b*256 + n] = fmaxf(acc, 0.f);
}

// ---------------- protein branch ----------------

// transpose conv_w (OIH: [32,1000,8]) -> cwT [i][o*8+k]
__global__ __launch_bounds__(256) void k_cw_transpose(
    const float* __restrict__ cw, float* __restrict__ cwT)
{
    int g = blockIdx.x*256 + threadIdx.x;   // 256000 total
    int i = g >> 8;
    int j = g & 255;
    int o = j >> 3, k = j & 7;
    cwT[g] = cw[o*(PLEN*KS) + i*KS + k];
}

// per-graph: bucket conv weights by vocab symbol, then small conv
__global__ __launch_bounds__(256) void k_conv(
    const int* __restrict__ target, const float* __restrict__ emb,
    const float* __restrict__ cwT, const float* __restrict__ conv_b,
    float* __restrict__ c)
{
    __shared__ float embS[VOCAB*EMBD];   // 3328 f
    __shared__ float Gs[VOCAB*256];      // 6656 f
    __shared__ int   tgtS[PLEN];
    __shared__ float cbS[NF];
    int b = blockIdx.x, j = threadIdx.x;
    for (int i=j; i<VOCAB*EMBD; i+=256) embS[i] = emb[i];
    for (int i=j; i<VOCAB*256; i+=256) Gs[i] = 0.f;
    for (int i=j; i<PLEN; i+=256) tgtS[i] = target[b*PLEN+i];
    if (j < NF) cbS[j] = conv_b[j];
    __syncthreads();
    #pragma unroll 4
    for (int i=0; i<PLEN; ++i) {
        int v = tgtS[i];
        Gs[v*256 + j] += cwT[i*256 + j];
    }
    __syncthreads();
    for (int idx=j; idx<FCX; idx+=256) {
        int o = idx / CLEN, tt = idx - o*CLEN;
        float acc = cbS[o];
        for (int v=0; v<VOCAB; ++v) {
            #pragma unroll
            for (int k=0; k<KS; ++k)
                acc += embS[v*EMBD + tt + k] * Gs[v*256 + o*KS + k];
        }
        c[(long)b*FCX + idx] = acc;
    }
}

// xt = c @ w_fcxt + b -> xc[:, 128:256]; 4 graphs per block
__global__ __launch_bounds__(128) void k_xt(
    const float* __restrict__ c, const float* __restrict__ w,
    const float* __restrict__ bias, float* __restrict__ xc)
{
    __shared__ float cS[4][FCX];   // 61952 B
    int b0 = blockIdx.x*4, n = threadIdx.x;
    for (int q=0; q<4; ++q)
        for (int i=n; i<FCX; i+=128) cS[q][i] = c[(long)(b0+q)*FCX + i];
    __syncthreads();
    float a0=bias[n], a1=a0, a2=a0, a3=a0;
    for (int r=0; r<FCX; ++r) {
        float wv = w[(long)r*OUTD + n];
        a0 += cS[0][r]*wv; a1 += cS[1][r]*wv;
        a2 += cS[2][r]*wv; a3 += cS[3][r]*wv;
    }
    xc[(b0+0)*256+128+n]=a0; xc[(b0+1)*256+128+n]=a1;
    xc[(b0+2)*256+128+n]=a2; xc[(b0+3)*256+128+n]=a3;
}

// ---------------- joint head ----------------

__global__ __launch_bounds__(256) void k_fc1(
    const float* __restrict__ xc, const float* __restrict__ w,
    const float* __restrict__ bias, float* __restrict__ y)
{
    __shared__ float xS[4][256];
    int b0 = blockIdx.x*4, n = threadIdx.x;
    #pragma unroll
    for (int q=0; q<4; ++q) xS[q][n] = xc[(b0+q)*256 + n];
    __syncthreads();
    float acc[4][4];
    #pragma unroll
    for (int m=0; m<4; ++m) {
        float bv = bias[m*256+n];
        #pragma unroll
        for (int q=0; q<4; ++q) acc[q][m] = bv;
    }
    for (int r=0; r<256; ++r) {
        float x0=xS[0][r], x1=xS[1][r], x2=xS[2][r], x3=xS[3][r];
        #pragma unroll
        for (int m=0; m<4; ++m) {
            float wv = w[r*1024 + m*256 + n];
            acc[0][m]+=x0*wv; acc[1][m]+=x1*wv; acc[2][m]+=x2*wv; acc[3][m]+=x3*wv;
        }
    }
    #pragma unroll
    for (int q=0; q<4; ++q)
        #pragma unroll
        for (int m=0; m<4; ++m)
            y[(b0+q)*1024 + m*256 + n] = fmaxf(acc[q][m], 0.f);
}

__global__ __launch_bounds__(256) void k_fc2(
    const float* __restrict__ y, const float* __restrict__ w,
    const float* __restrict__ bias, float* __restrict__ y2)
{
    __shared__ float xS[4][1024];
    int b0 = blockIdx.x*4, n = threadIdx.x;
    #pragma unroll
    for (int q=0; q<4; ++q)
        for (int i=n; i<1024; i+=256) xS[q][i] = y[(b0+q)*1024 + i];
    __syncthreads();
    float acc[4];
    #pragma unroll
    for (int q=0; q<4; ++q) acc[q] = bias[n];
    for (int r=0; r<1024; ++r) {
        float wv = w[r*256 + n];
        #pragma unroll
        for (int q=0; q<4; ++q) acc[q] += xS[q][r]*wv;
    }
    #pragma unroll
    for (int q=0; q<4; ++q) y2[(b0+q)*256 + n] = fmaxf(acc[q], 0.f);
}

__global__ __launch_bounds__(256) void k_out(
    const float* __restrict__ y2, const float* __restrict__ w,
    const float* __restrict__ bias, float* __restrict__ out)
{
    int b = blockIdx.x, n = threadIdx.x;
    float v = y2[b*256 + n] * w[n];
    #pragma unroll
    for (int off=32; off; off>>=1) v += __shfl_down(v, off, 64);
    __shared__ float red[4];
    if ((n & 63) == 0) red[n >> 6] = v;
    __syncthreads();
    if (n == 0) out[b] = red[0]+red[1]+red[2]+red[3] + bias[0];
}

// ---------------- launch ----------------

extern "C" void kernel_launch(void* const* d_in, const int* in_sizes, int n_in,
                              void* d_out, int out_size, void* d_ws, size_t ws_size,
                              hipStream_t stream) {
    const float* x      = (const float*)d_in[0];
    const int*   ei     = (const int*)  d_in[1];
    const int*   batch  = (const int*)  d_in[2];
    const int*   target = (const int*)  d_in[3];
    const float* w1a    = (const float*)d_in[4];
    const float* b1a    = (const float*)d_in[5];
    const float* w1b    = (const float*)d_in[6];
    const float* b1b    = (const float*)d_in[7];
    const float* wa     = (const float*)d_in[8];
    const float* ba     = (const float*)d_in[9];
    const float* wb     = (const float*)d_in[10];
    const float* bb     = (const float*)d_in[11];
    const float* gamma  = (const float*)d_in[12];
    const float* beta   = (const float*)d_in[13];
    const float* w_fcxd = (const float*)d_in[14];
    const float* b_fcxd = (const float*)d_in[15];
    const float* emb    = (const float*)d_in[16];
    const float* conv_w = (const float*)d_in[17];
    const float* conv_b = (const float*)d_in[18];
    const float* w_fcxt = (const float*)d_in[19];
    const float* b_fcxt = (const float*)d_in[20];
    const float* w_fc1  = (const float*)d_in[21];
    const float* b_fc1  = (const float*)d_in[22];
    const float* w_fc2  = (const float*)d_in[23];
    const float* b_fc2  = (const float*)d_in[24];
    const float* w_out  = (const float*)d_in[25];
    const float* b_out  = (const float*)d_in[26];

    float* ws    = (float*)d_ws;
    float* t_buf = ws;                       // N*32
    float* agg   = t_buf + (size_t)N_NODES*DIM;
    float* z     = agg   + (size_t)N_NODES*DIM;
    float* stats = z     + (size_t)N_NODES*DIM;   // 64
    float* ss    = stats + 64;                    // 64
    float* hg    = ss    + 64;                    // NB*32
    float* cwT   = hg    + (size_t)NB*DIM;        // 256000
    float* cbuf  = cwT   + 256000;                // NB*3872
    float* xc    = cbuf  + (size_t)NB*FCX;        // NB*256
    float* y1    = xc    + (size_t)NB*256;        // NB*1024
    float* y2    = y1    + (size_t)NB*1024;       // NB*256

    // protein branch (independent of GIN chain)
    k_cw_transpose<<<1000, 256, 0, stream>>>(conv_w, cwT);
    k_conv<<<NB, 256, 0, stream>>>(target, emb, cwT, conv_b, cbuf);

    // GIN layers
    for (int l=0; l<5; ++l) {
        if (l == 0)
            k_l1_transform<<<N_NODES/256, 256, 0, stream>>>(x, w1a, t_buf, agg);
        else
            k_transform<<<N_NODES/256, 256, 0, stream>>>(z, ss, wa + (size_t)(l-1)*DIM*DIM, t_buf, agg);
        k_edges<<<(N_EDGES*32)/256, 256, 0, stream>>>(ei, t_buf, agg);
        hipMemsetAsync(stats, 0, 64*sizeof(float), stream);
        const float* bi = (l==0) ? b1a : ba + (size_t)(l-1)*DIM;
        const float* wo = (l==0) ? w1b : wb + (size_t)(l-1)*DIM*DIM;
        const float* bo = (l==0) ? b1b : bb + (size_t)(l-1)*DIM;
        k_mlp<<<N_NODES/256, 256, 0, stream>>>(agg, bi, wo, bo, z, stats);
        k_scaleshift<<<1, 32, 0, stream>>>(stats, gamma, beta, l, ss);
    }

    // pool + drug head
    hipMemsetAsync(hg, 0, (size_t)NB*DIM*sizeof(float), stream);
    k_pool<<<(N_NODES*32)/256, 256, 0, stream>>>(z, ss, batch, hg);
    k_xd<<<NB, 128, 0, stream>>>(hg, w_fcxd, b_fcxd, xc);
    k_xt<<<NB/4, 128, 0, stream>>>(cbuf, w_fcxt, b_fcxt, xc);

    // joint head
    k_fc1<<<NB/4, 256, 0, stream>>>(xc, w_fc1, b_fc1, y1);
    k_fc2<<<NB/4, 256, 0, stream>>>(y1, w_fc2, b_fc2, y2);
    k_out<<<NB, 256, 0, stream>>>(y2, w_out, b_out, (float*)d_out);
}

// Round 2
// 1959.297 us; speedup vs baseline: 1.0399x; 1.0399x over previous
//
#include <hip/hip_runtime.h>

#define N_NODES 65536
#define N_EDGES 2097152
#define NB      1024
#define FXD     78
#define DIM     32
#define EMBD    128
#define OUTD    128
#define VOCAB   26
#define PLEN    1000
#define KS      8
#define CLEN    121      // EMBD-KS+1
#define NF      32
#define FCX     (NF*CLEN)  // 3872

// ---------------- CSR build ----------------

__global__ __launch_bounds__(256) void k_deg(
    const int* __restrict__ ei, int* __restrict__ deg)
{
    int e = blockIdx.x*256 + threadIdx.x;
    atomicAdd(&deg[ei[N_EDGES + e]], 1);
}

// per-256-block exclusive scan; writes local prefix into rowptr, block total into bsum
__global__ __launch_bounds__(256) void k_scan1(
    const int* __restrict__ deg, int* __restrict__ rowptr, int* __restrict__ bsum)
{
    __shared__ int s[256];
    int n = blockIdx.x*256 + threadIdx.x;
    int v = deg[n];
    s[threadIdx.x] = v;
    __syncthreads();
    for (int off=1; off<256; off<<=1) {
        int tv = (threadIdx.x >= off) ? s[threadIdx.x-off] : 0;
        __syncthreads();
        s[threadIdx.x] += tv;
        __syncthreads();
    }
    rowptr[n] = s[threadIdx.x] - v;     // exclusive
    if (threadIdx.x == 255) bsum[blockIdx.x] = s[255];
}

__global__ __launch_bounds__(256) void k_scan2(
    const int* __restrict__ bsum, int* __restrict__ boffs)
{
    __shared__ int s[256];
    int v = bsum[threadIdx.x];
    s[threadIdx.x] = v;
    __syncthreads();
    for (int off=1; off<256; off<<=1) {
        int tv = (threadIdx.x >= off) ? s[threadIdx.x-off] : 0;
        __syncthreads();
        s[threadIdx.x] += tv;
        __syncthreads();
    }
    boffs[threadIdx.x] = s[threadIdx.x] - v;  // exclusive
}

__global__ __launch_bounds__(256) void k_scan3(
    int* __restrict__ rowptr, const int* __restrict__ boffs, int* __restrict__ cursor)
{
    int n = blockIdx.x*256 + threadIdx.x;
    int r = rowptr[n] + boffs[n >> 8];
    rowptr[n] = r;
    cursor[n] = r;
    if (n == 0) rowptr[N_NODES] = N_EDGES;
}

__global__ __launch_bounds__(256) void k_fill(
    const int* __restrict__ ei, int* __restrict__ cursor, int* __restrict__ csr)
{
    int e = blockIdx.x*256 + threadIdx.x;
    int s = ei[e];
    int d = ei[N_EDGES + e];
    int pos = atomicAdd(&cursor[d], 1);
    csr[pos] = s;
}

// ---------------- GIN layer kernels ----------------

// Layer-1 transform: t = x @ w1a
__global__ __launch_bounds__(256) void k_l1_transform(
    const float* __restrict__ x, const float* __restrict__ w,
    float* __restrict__ t)
{
    __shared__ float wS[FXD*DIM];
    for (int i = threadIdx.x; i < FXD*DIM; i += 256) wS[i] = w[i];
    __syncthreads();
    int node = blockIdx.x*256 + threadIdx.x;
    float acc[DIM];
    #pragma unroll
    for (int d=0; d<DIM; ++d) acc[d] = 0.f;
    const float* xr = x + (long)node*FXD;
    for (int j=0; j<FXD; ++j) {
        float xv = xr[j];
        #pragma unroll
        for (int d=0; d<DIM; ++d) acc[d] += xv * wS[j*DIM+d];
    }
    float4* t4 = (float4*)(t + (long)node*DIM);
    #pragma unroll
    for (int q=0; q<DIM/4; ++q)
        t4[q] = make_float4(acc[q*4],acc[q*4+1],acc[q*4+2],acc[q*4+3]);
}

// Layers 2-5 transform: h = BN(z) via scale/shift; t = h @ w
__global__ __launch_bounds__(256) void k_transform(
    const float* __restrict__ z, const float* __restrict__ ss,
    const float* __restrict__ w, float* __restrict__ t)
{
    __shared__ float wS[DIM*DIM];
    __shared__ float sS[2*DIM];
    for (int i = threadIdx.x; i < DIM*DIM; i += 256) wS[i] = w[i];
    if (threadIdx.x < 2*DIM) sS[threadIdx.x] = ss[threadIdx.x];
    __syncthreads();
    int node = blockIdx.x*256 + threadIdx.x;
    float h[DIM];
    const float4* z4 = (const float4*)(z + (long)node*DIM);
    #pragma unroll
    for (int q=0; q<DIM/4; ++q) {
        float4 v = z4[q];
        h[q*4+0]=v.x; h[q*4+1]=v.y; h[q*4+2]=v.z; h[q*4+3]=v.w;
    }
    #pragma unroll
    for (int d=0; d<DIM; ++d) h[d] = h[d]*sS[d] + sS[DIM+d];
    float acc[DIM];
    #pragma unroll
    for (int d=0; d<DIM; ++d) acc[d] = 0.f;
    #pragma unroll
    for (int j=0; j<DIM; ++j) {
        float hv = h[j];
        #pragma unroll
        for (int d=0; d<DIM; ++d) acc[d] += hv * wS[j*DIM+d];
    }
    float4* t4 = (float4*)(t + (long)node*DIM);
    #pragma unroll
    for (int q=0; q<DIM/4; ++q)
        t4[q] = make_float4(acc[q*4],acc[q*4+1],acc[q*4+2],acc[q*4+3]);
}

// Gather (CSR) + self + MLP + ReLU + BN-stats. 8 nodes/block, 32 lanes/node.
__global__ __launch_bounds__(256) void k_gather_mlp(
    const int* __restrict__ rowptr, const int* __restrict__ csr,
    const float* __restrict__ t,
    const float* __restrict__ bi, const float* __restrict__ wo, const float* __restrict__ bo,
    float* __restrict__ z, float* __restrict__ stats)
{
    __shared__ float wS[DIM*DIM];
    __shared__ float bS[2*DIM];
    __shared__ float stS[2*DIM];
    int tid = threadIdx.x;
    for (int i=tid; i<DIM*DIM; i+=256) wS[i]=wo[i];
    if (tid<DIM) bS[tid]=bi[tid];
    else if (tid<2*DIM) bS[tid]=bo[tid-DIM];
    if (tid<2*DIM) stS[tid]=0.f;
    __syncthreads();
    int node = blockIdx.x*8 + (tid>>5);
    int c = tid & 31;
    float acc = t[(long)node*DIM + c];      // self term
    int s0 = rowptr[node], s1 = rowptr[node+1];
    int e = s0;
    for (; e+4 <= s1; e+=4) {
        int i0=csr[e], i1=csr[e+1], i2=csr[e+2], i3=csr[e+3];
        float v0=t[(long)i0*DIM+c], v1=t[(long)i1*DIM+c],
              v2=t[(long)i2*DIM+c], v3=t[(long)i3*DIM+c];
        acc += (v0+v1)+(v2+v3);
    }
    for (; e<s1; ++e) acc += t[(long)csr[e]*DIM + c];
    float u = fmaxf(acc + bS[c], 0.f);
    float zz = bS[DIM+c];
    #pragma unroll
    for (int j=0; j<DIM; ++j) {
        float uj = __shfl(u, j, 32);
        zz += uj * wS[j*DIM+c];
    }
    zz = fmaxf(zz, 0.f);
    z[(long)node*DIM + c] = zz;
    // stats: reduce the two 32-groups of each wave, then LDS atomics
    float zs = zz + __shfl_down(zz, 32, 64);
    float zq = zz*zz;
    zq = zq + __shfl_down(zq, 32, 64);
    if ((tid & 32) == 0) {
        atomicAdd(&stS[c], zs);
        atomicAdd(&stS[DIM+c], zq);
    }
    __syncthreads();
    if (tid < 2*DIM) atomicAdd(&stats[tid], stS[tid]);
}

// computes scale/shift from stats, then zeroes stats for the next layer
__global__ void k_scaleshift(const float* __restrict__ statsIn,
                             float* __restrict__ statsClr,
                             const float* __restrict__ gamma, const float* __restrict__ beta,
                             int layer, float* __restrict__ ss)
{
    int d = threadIdx.x;
    if (d < DIM) {
        float mean = statsIn[d] * (1.f/N_NODES);
        float var  = statsIn[DIM+d] * (1.f/N_NODES) - mean*mean;
        float sc = gamma[layer*DIM+d] * rsqrtf(var + 1e-5f);
        ss[d] = sc;
        ss[DIM+d] = beta[layer*DIM+d] - mean*sc;
    }
    if (d < 2*DIM) statsClr[d] = 0.f;
}

// Global add pool with BN applied: hg[batch[n]] += BN(z[n])
__global__ __launch_bounds__(256) void k_pool(
    const float* __restrict__ z, const float* __restrict__ ss,
    const int* __restrict__ batch, float* __restrict__ hg)
{
    long g = (long)blockIdx.x*256 + threadIdx.x;
    int node = (int)(g >> 5);
    int c = (int)(g & 31);
    int b = batch[node];
    float v = z[(long)node*DIM + c]*ss[c] + ss[DIM+c];
    atomicAdd(&hg[b*DIM + c], v);
}

// xd = ReLU(hg @ w_fcxd + b) -> xc[:, 0:128]
__global__ __launch_bounds__(128) void k_xd(
    const float* __restrict__ hg, const float* __restrict__ w,
    const float* __restrict__ bias, float* __restrict__ xc)
{
    int b = blockIdx.x, n = threadIdx.x;
    __shared__ float hS[DIM];
    if (n < DIM) hS[n] = hg[b*DIM+n];
    __syncthreads();
    float acc = bias[n];
    #pragma unroll
    for (int r=0; r<DIM; ++r) acc += hS[r]*w[r*OUTD+n];
    xc[b*256 + n] = fmaxf(acc, 0.f);
}

// ---------------- protein branch ----------------

// transpose conv_w (OIH: [32,1000,8]) -> cwT [i][o*8+k]
__global__ __launch_bounds__(256) void k_cw_transpose(
    const float* __restrict__ cw, float* __restrict__ cwT)
{
    int g = blockIdx.x*256 + threadIdx.x;   // 256000 total
    int i = g >> 8;
    int j = g & 255;
    int o = j >> 3, k = j & 7;
    cwT[g] = cw[o*(PLEN*KS) + i*KS + k];
}

// per-graph: counting-sort positions by symbol, register-bucket conv weights,
// then register-cached small conv.
__global__ __launch_bounds__(256) void k_conv(
    const int* __restrict__ target, const float* __restrict__ emb,
    const float* __restrict__ cwT, const float* __restrict__ conv_b,
    float* __restrict__ c)
{
    __shared__ float embS[VOCAB*EMBD + 8];  // padded: sliding-window over-read stays in-bounds
    __shared__ float Gs[VOCAB*256];         // also reused as output stage
    __shared__ int   sortedS[PLEN];
    __shared__ int   cntS[VOCAB];
    __shared__ int   segS[VOCAB+1];
    __shared__ int   curS[VOCAB];
    __shared__ float cbS[NF];
    int b = blockIdx.x, j = threadIdx.x;
    for (int i=j; i<VOCAB*EMBD; i+=256) embS[i] = emb[i];
    if (j < VOCAB) cntS[j] = 0;
    if (j < NF) cbS[j] = conv_b[j];
    __syncthreads();
    int tloc[4];
    #pragma unroll
    for (int q=0; q<4; ++q) {
        int i = j + q*256;
        if (i < PLEN) {
            tloc[q] = target[b*PLEN+i];
            atomicAdd(&cntS[tloc[q]], 1);
        } else tloc[q] = -1;
    }
    __syncthreads();
    if (j == 0) {
        int run = 0;
        for (int v=0; v<VOCAB; ++v) { segS[v]=run; run += cntS[v]; }
        segS[VOCAB] = run;
    }
    __syncthreads();
    if (j < VOCAB) curS[j] = segS[j];
    __syncthreads();
    #pragma unroll
    for (int q=0; q<4; ++q) {
        int i = j + q*256;
        if (i < PLEN) {
            int pos = atomicAdd(&curS[tloc[q]], 1);
            sortedS[pos] = i;
        }
    }
    __syncthreads();
    // bucket-accumulate: register acc per symbol run, one LDS write per v
    for (int v=0; v<VOCAB; ++v) {
        int s = segS[v], e2 = segS[v+1];
        float acc = 0.f;
        int p = s;
        for (; p+4 <= e2; p += 4) {
            int i0=sortedS[p], i1=sortedS[p+1], i2=sortedS[p+2], i3=sortedS[p+3];
            acc += cwT[i0*256+j] + cwT[i1*256+j] + cwT[i2*256+j] + cwT[i3*256+j];
        }
        for (; p<e2; ++p) acc += cwT[sortedS[p]*256+j];
        Gs[v*256+j] = acc;
    }
    __syncthreads();
    // conv: thread j -> o = j>>3, tt block of 16 starting at (j&7)*16
    int o = j >> 3, pg = j & 7;
    int t0 = pg*16;
    int tcnt = (t0+16 <= CLEN) ? 16 : (CLEN - t0);   // 16 or 9
    float out[16];
    #pragma unroll
    for (int q=0; q<16; ++q) out[q] = cbS[o];
    for (int v=0; v<VOCAB; ++v) {
        float g[KS];
        #pragma unroll
        for (int k=0; k<KS; ++k) g[k] = Gs[v*256 + o*KS + k];
        float e[23];
        const float* ev = &embS[v*EMBD + t0];
        #pragma unroll
        for (int m=0; m<23; ++m) e[m] = ev[m];
        #pragma unroll
        for (int q=0; q<16; ++q) {
            float s = 0.f;
            #pragma unroll
            for (int k=0; k<KS; ++k) s += e[q+k]*g[k];
            out[q] += s;
        }
    }
    __syncthreads();
    // stage to LDS (reuse Gs) then coalesced store
    float* stage = Gs;
    for (int q=0; q<tcnt; ++q) stage[o*CLEN + t0 + q] = out[q];
    __syncthreads();
    for (int idx=j; idx<FCX; idx+=256)
        c[(long)b*FCX + idx] = stage[idx];
}

// xt = c @ w_fcxt + b -> xc[:, 128:256]; 4 graphs per block
__global__ __launch_bounds__(128) void k_xt(
    const float* __restrict__ c, const float* __restrict__ w,
    const float* __restrict__ bias, float* __restrict__ xc)
{
    __shared__ float cS[4][FCX];   // 61952 B
    int b0 = blockIdx.x*4, n = threadIdx.x;
    for (int q=0; q<4; ++q)
        for (int i=n; i<FCX; i+=128) cS[q][i] = c[(long)(b0+q)*FCX + i];
    __syncthreads();
    float a0=bias[n], a1=a0, a2=a0, a3=a0;
    for (int r=0; r<FCX; ++r) {
        float wv = w[(long)r*OUTD + n];
        a0 += cS[0][r]*wv; a1 += cS[1][r]*wv;
        a2 += cS[2][r]*wv; a3 += cS[3][r]*wv;
    }
    xc[(b0+0)*256+128+n]=a0; xc[(b0+1)*256+128+n]=a1;
    xc[(b0+2)*256+128+n]=a2; xc[(b0+3)*256+128+n]=a3;
}

// ---------------- joint head ----------------

__global__ __launch_bounds__(256) void k_fc1(
    const float* __restrict__ xc, const float* __restrict__ w,
    const float* __restrict__ bias, float* __restrict__ y)
{
    __shared__ float xS[4][256];
    int b0 = blockIdx.x*4, n = threadIdx.x;
    #pragma unroll
    for (int q=0; q<4; ++q) xS[q][n] = xc[(b0+q)*256 + n];
    __syncthreads();
    float acc[4][4];
    #pragma unroll
    for (int m=0; m<4; ++m) {
        float bv = bias[m*256+n];
        #pragma unroll
        for (int q=0; q<4; ++q) acc[q][m] = bv;
    }
    for (int r=0; r<256; ++r) {
        float x0=xS[0][r], x1=xS[1][r], x2=xS[2][r], x3=xS[3][r];
        #pragma unroll
        for (int m=0; m<4; ++m) {
            float wv = w[r*1024 + m*256 + n];
            acc[0][m]+=x0*wv; acc[1][m]+=x1*wv; acc[2][m]+=x2*wv; acc[3][m]+=x3*wv;
        }
    }
    #pragma unroll
    for (int q=0; q<4; ++q)
        #pragma unroll
        for (int m=0; m<4; ++m)
            y[(b0+q)*1024 + m*256 + n] = fmaxf(acc[q][m], 0.f);
}

__global__ __launch_bounds__(256) void k_fc2(
    const float* __restrict__ y, const float* __restrict__ w,
    const float* __restrict__ bias, float* __restrict__ y2)
{
    __shared__ float xS[4][1024];
    int b0 = blockIdx.x*4, n = threadIdx.x;
    #pragma unroll
    for (int q=0; q<4; ++q)
        for (int i=n; i<1024; i+=256) xS[q][i] = y[(b0+q)*1024 + i];
    __syncthreads();
    float acc[4];
    #pragma unroll
    for (int q=0; q<4; ++q) acc[q] = bias[n];
    for (int r=0; r<1024; ++r) {
        float wv = w[r*256 + n];
        #pragma unroll
        for (int q=0; q<4; ++q) acc[q] += xS[q][r]*wv;
    }
    #pragma unroll
    for (int q=0; q<4; ++q) y2[(b0+q)*256 + n] = fmaxf(acc[q], 0.f);
}

__global__ __launch_bounds__(256) void k_out(
    const float* __restrict__ y2, const float* __restrict__ w,
    const float* __restrict__ bias, float* __restrict__ out)
{
    int b = blockIdx.x, n = threadIdx.x;
    float v = y2[b*256 + n] * w[n];
    #pragma unroll
    for (int off=32; off; off>>=1) v += __shfl_down(v, off, 64);
    __shared__ float red[4];
    if ((n & 63) == 0) red[n >> 6] = v;
    __syncthreads();
    if (n == 0) out[b] = red[0]+red[1]+red[2]+red[3] + bias[0];
}

// ---------------- launch ----------------

extern "C" void kernel_launch(void* const* d_in, const int* in_sizes, int n_in,
                              void* d_out, int out_size, void* d_ws, size_t ws_size,
                              hipStream_t stream) {
    const float* x      = (const float*)d_in[0];
    const int*   ei     = (const int*)  d_in[1];
    const int*   batch  = (const int*)  d_in[2];
    const int*   target = (const int*)  d_in[3];
    const float* w1a    = (const float*)d_in[4];
    const float* b1a    = (const float*)d_in[5];
    const float* w1b    = (const float*)d_in[6];
    const float* b1b    = (const float*)d_in[7];
    const float* wa     = (const float*)d_in[8];
    const float* ba     = (const float*)d_in[9];
    const float* wb     = (const float*)d_in[10];
    const float* bb     = (const float*)d_in[11];
    const float* gamma  = (const float*)d_in[12];
    const float* beta   = (const float*)d_in[13];
    const float* w_fcxd = (const float*)d_in[14];
    const float* b_fcxd = (const float*)d_in[15];
    const float* emb    = (const float*)d_in[16];
    const float* conv_w = (const float*)d_in[17];
    const float* conv_b = (const float*)d_in[18];
    const float* w_fcxt = (const float*)d_in[19];
    const float* b_fcxt = (const float*)d_in[20];
    const float* w_fc1  = (const float*)d_in[21];
    const float* b_fc1  = (const float*)d_in[22];
    const float* w_fc2  = (const float*)d_in[23];
    const float* b_fc2  = (const float*)d_in[24];
    const float* w_out  = (const float*)d_in[25];
    const float* b_out  = (const float*)d_in[26];

    float* ws     = (float*)d_ws;
    float* t_buf  = ws;                                   // 2M
    float* z      = t_buf + (size_t)N_NODES*DIM;          // 2M
    int*   csr    = (int*)(z + (size_t)N_NODES*DIM);      // 2M
    int*   rowptr = csr + N_EDGES;                        // 65544 (N+1 padded)
    int*   cursor = rowptr + (N_NODES + 8);               // 65536
    int*   bsum   = cursor + N_NODES;                     // 256
    int*   boffs  = bsum + 256;                           // 256
    float* stats  = (float*)(boffs + 256);                // 64
    float* ss     = stats + 64;                           // 64
    float* hg     = ss + 64;                              // 32768
    float* cwT    = hg + (size_t)NB*DIM;                  // 256000
    float* cbuf   = cwT + 256000;                         // 3964928
    float* xc     = cbuf + (size_t)NB*FCX;                // 262144
    float* y1     = xc + (size_t)NB*256;                  // 1048576
    float* y2     = y1 + (size_t)NB*1024;                 // 262144

    // ---- CSR build (cursor doubles as deg buffer) ----
    hipMemsetAsync(cursor, 0, N_NODES*sizeof(int), stream);
    k_deg<<<N_EDGES/256, 256, 0, stream>>>(ei, cursor);
    k_scan1<<<N_NODES/256, 256, 0, stream>>>(cursor, rowptr, bsum);
    k_scan2<<<1, 256, 0, stream>>>(bsum, boffs);
    k_scan3<<<N_NODES/256, 256, 0, stream>>>(rowptr, boffs, cursor);
    k_fill<<<N_EDGES/256, 256, 0, stream>>>(ei, cursor, csr);

    // ---- protein branch ----
    k_cw_transpose<<<1000, 256, 0, stream>>>(conv_w, cwT);
    k_conv<<<NB, 256, 0, stream>>>(target, emb, cwT, conv_b, cbuf);

    // ---- GIN layers ----
    hipMemsetAsync(stats, 0, 64*sizeof(float), stream);
    for (int l=0; l<5; ++l) {
        if (l == 0)
            k_l1_transform<<<N_NODES/256, 256, 0, stream>>>(x, w1a, t_buf);
        else
            k_transform<<<N_NODES/256, 256, 0, stream>>>(z, ss, wa + (size_t)(l-1)*DIM*DIM, t_buf);
        const float* bi = (l==0) ? b1a : ba + (size_t)(l-1)*DIM;
        const float* wo = (l==0) ? w1b : wb + (size_t)(l-1)*DIM*DIM;
        const float* bo = (l==0) ? b1b : bb + (size_t)(l-1)*DIM;
        k_gather_mlp<<<N_NODES/8, 256, 0, stream>>>(rowptr, csr, t_buf, bi, wo, bo, z, stats);
        k_scaleshift<<<1, 64, 0, stream>>>(stats, stats, gamma, beta, l, ss);
    }

    // ---- pool + drug head ----
    hipMemsetAsync(hg, 0, (size_t)NB*DIM*sizeof(float), stream);
    k_pool<<<(N_NODES*32)/256, 256, 0, stream>>>(z, ss, batch, hg);
    k_xd<<<NB, 128, 0, stream>>>(hg, w_fcxd, b_fcxd, xc);
    k_xt<<<NB/4, 128, 0, stream>>>(cbuf, w_fcxt, b_fcxt, xc);

    // ---- joint head ----
    k_fc1<<<NB/4, 256, 0, stream>>>(xc, w_fc1, b_fc1, y1);
    k_fc2<<<NB/4, 256, 0, stream>>>(y1, w_fc2, b_fc2, y2);
    k_out<<<NB, 256, 0, stream>>>(y2, w_out, b_out, (float*)d_out);
}

// Round 3
// 1162.564 us; speedup vs baseline: 1.7526x; 1.6853x over previous
//
#include <hip/hip_runtime.h>

#define N_NODES 65536
#define N_EDGES 2097152
#define NB      1024
#define FXD     78
#define DIM     32
#define EMBD    128
#define OUTD    128
#define VOCAB   26
#define PLEN    1000
#define KS      8
#define CLEN    121      // EMBD-KS+1
#define NF      32
#define FCX     (NF*CLEN)  // 3872
#define NSLICE  256      // stats partial slices

// ---------------- CSR build ----------------

__global__ __launch_bounds__(256) void k_deg(
    const int* __restrict__ ei, int* __restrict__ deg)
{
    int e = blockIdx.x*256 + threadIdx.x;
    atomicAdd(&deg[ei[N_EDGES + e]], 1);
}

__global__ __launch_bounds__(256) void k_scan1(
    const int* __restrict__ deg, int* __restrict__ rowptr, int* __restrict__ bsum)
{
    __shared__ int s[256];
    int n = blockIdx.x*256 + threadIdx.x;
    int v = deg[n];
    s[threadIdx.x] = v;
    __syncthreads();
    for (int off=1; off<256; off<<=1) {
        int tv = (threadIdx.x >= off) ? s[threadIdx.x-off] : 0;
        __syncthreads();
        s[threadIdx.x] += tv;
        __syncthreads();
    }
    rowptr[n] = s[threadIdx.x] - v;     // exclusive
    if (threadIdx.x == 255) bsum[blockIdx.x] = s[255];
}

__global__ __launch_bounds__(256) void k_scan2(
    const int* __restrict__ bsum, int* __restrict__ boffs)
{
    __shared__ int s[256];
    int v = bsum[threadIdx.x];
    s[threadIdx.x] = v;
    __syncthreads();
    for (int off=1; off<256; off<<=1) {
        int tv = (threadIdx.x >= off) ? s[threadIdx.x-off] : 0;
        __syncthreads();
        s[threadIdx.x] += tv;
        __syncthreads();
    }
    boffs[threadIdx.x] = s[threadIdx.x] - v;  // exclusive
}

__global__ __launch_bounds__(256) void k_scan3(
    int* __restrict__ rowptr, const int* __restrict__ boffs, int* __restrict__ cursor)
{
    int n = blockIdx.x*256 + threadIdx.x;
    int r = rowptr[n] + boffs[n >> 8];
    rowptr[n] = r;
    cursor[n] = r;
    if (n == 0) rowptr[N_NODES] = N_EDGES;
}

__global__ __launch_bounds__(256) void k_fill(
    const int* __restrict__ ei, int* __restrict__ cursor, int* __restrict__ csr)
{
    int e = blockIdx.x*256 + threadIdx.x;
    int s = ei[e];
    int d = ei[N_EDGES + e];
    int pos = atomicAdd(&cursor[d], 1);
    csr[pos] = s;
}

// ---------------- GIN layer kernels ----------------

__global__ __launch_bounds__(256) void k_l1_transform(
    const float* __restrict__ x, const float* __restrict__ w,
    float* __restrict__ t)
{
    __shared__ float wS[FXD*DIM];
    for (int i = threadIdx.x; i < FXD*DIM; i += 256) wS[i] = w[i];
    __syncthreads();
    int node = blockIdx.x*256 + threadIdx.x;
    float acc[DIM];
    #pragma unroll
    for (int d=0; d<DIM; ++d) acc[d] = 0.f;
    const float* xr = x + (long)node*FXD;
    for (int j=0; j<FXD; ++j) {
        float xv = xr[j];
        #pragma unroll
        for (int d=0; d<DIM; ++d) acc[d] += xv * wS[j*DIM+d];
    }
    float4* t4 = (float4*)(t + (long)node*DIM);
    #pragma unroll
    for (int q=0; q<DIM/4; ++q)
        t4[q] = make_float4(acc[q*4],acc[q*4+1],acc[q*4+2],acc[q*4+3]);
}

__global__ __launch_bounds__(256) void k_transform(
    const float* __restrict__ z, const float* __restrict__ ss,
    const float* __restrict__ w, float* __restrict__ t)
{
    __shared__ float wS[DIM*DIM];
    __shared__ float sS[2*DIM];
    for (int i = threadIdx.x; i < DIM*DIM; i += 256) wS[i] = w[i];
    if (threadIdx.x < 2*DIM) sS[threadIdx.x] = ss[threadIdx.x];
    __syncthreads();
    int node = blockIdx.x*256 + threadIdx.x;
    float h[DIM];
    const float4* z4 = (const float4*)(z + (long)node*DIM);
    #pragma unroll
    for (int q=0; q<DIM/4; ++q) {
        float4 v = z4[q];
        h[q*4+0]=v.x; h[q*4+1]=v.y; h[q*4+2]=v.z; h[q*4+3]=v.w;
    }
    #pragma unroll
    for (int d=0; d<DIM; ++d) h[d] = h[d]*sS[d] + sS[DIM+d];
    float acc[DIM];
    #pragma unroll
    for (int d=0; d<DIM; ++d) acc[d] = 0.f;
    #pragma unroll
    for (int j=0; j<DIM; ++j) {
        float hv = h[j];
        #pragma unroll
        for (int d=0; d<DIM; ++d) acc[d] += hv * wS[j*DIM+d];
    }
    float4* t4 = (float4*)(t + (long)node*DIM);
    #pragma unroll
    for (int q=0; q<DIM/4; ++q)
        t4[q] = make_float4(acc[q*4],acc[q*4+1],acc[q*4+2],acc[q*4+3]);
}

// Gather (CSR) + self + MLP + ReLU + BN-stats partials. 8 nodes/block, 32 lanes/node.
__global__ __launch_bounds__(256) void k_gather_mlp(
    const int* __restrict__ rowptr, const int* __restrict__ csr,
    const float* __restrict__ t,
    const float* __restrict__ bi, const float* __restrict__ wo, const float* __restrict__ bo,
    float* __restrict__ z, float* __restrict__ part)
{
    __shared__ float wS[DIM*DIM];
    __shared__ float bS[2*DIM];
    __shared__ float stS[2*DIM];
    int tid = threadIdx.x;
    for (int i=tid; i<DIM*DIM; i+=256) wS[i]=wo[i];
    if (tid<DIM) bS[tid]=bi[tid];
    else if (tid<2*DIM) bS[tid]=bo[tid-DIM];
    if (tid<2*DIM) stS[tid]=0.f;
    __syncthreads();
    int node = blockIdx.x*8 + (tid>>5);
    int c = tid & 31;
    float acc = t[(long)node*DIM + c];      // self term
    int s0 = rowptr[node], s1 = rowptr[node+1];
    int e = s0;
    for (; e+8 <= s1; e+=8) {
        int i0=csr[e],   i1=csr[e+1], i2=csr[e+2], i3=csr[e+3];
        int i4=csr[e+4], i5=csr[e+5], i6=csr[e+6], i7=csr[e+7];
        float v0=t[(long)i0*DIM+c], v1=t[(long)i1*DIM+c],
              v2=t[(long)i2*DIM+c], v3=t[(long)i3*DIM+c],
              v4=t[(long)i4*DIM+c], v5=t[(long)i5*DIM+c],
              v6=t[(long)i6*DIM+c], v7=t[(long)i7*DIM+c];
        acc += ((v0+v1)+(v2+v3)) + ((v4+v5)+(v6+v7));
    }
    for (; e+4 <= s1; e+=4) {
        int i0=csr[e], i1=csr[e+1], i2=csr[e+2], i3=csr[e+3];
        float v0=t[(long)i0*DIM+c], v1=t[(long)i1*DIM+c],
              v2=t[(long)i2*DIM+c], v3=t[(long)i3*DIM+c];
        acc += (v0+v1)+(v2+v3);
    }
    for (; e<s1; ++e) acc += t[(long)csr[e]*DIM + c];
    float u = fmaxf(acc + bS[c], 0.f);
    float zz = bS[DIM+c];
    #pragma unroll
    for (int j=0; j<DIM; ++j) {
        float uj = __shfl(u, j, 32);
        zz += uj * wS[j*DIM+c];
    }
    zz = fmaxf(zz, 0.f);
    z[(long)node*DIM + c] = zz;
    // stats: reduce the two 32-groups of each wave, then LDS, then per-slice global
    float zs = zz + __shfl_down(zz, 32, 64);
    float zq = zz*zz;
    zq = zq + __shfl_down(zq, 32, 64);
    if ((tid & 32) == 0) {
        atomicAdd(&stS[c], zs);
        atomicAdd(&stS[DIM+c], zq);
    }
    __syncthreads();
    if (tid < 2*DIM)
        atomicAdd(&part[((blockIdx.x & (NSLICE-1))<<6) + tid], stS[tid]);
}

// reduce partial stats -> scale/shift; re-zero partials for next layer
__global__ __launch_bounds__(256) void k_scaleshift(
    float* __restrict__ part,
    const float* __restrict__ gamma, const float* __restrict__ beta,
    int layer, float* __restrict__ ss)
{
    __shared__ float red[4][64];
    __shared__ float totS[64];
    int t = threadIdx.x;
    int ch = t & 63, q = t >> 6;
    float s = 0.f;
    for (int i = q*64; i < q*64 + 64; ++i) s += part[(i<<6) + ch];
    red[q][ch] = s;
    __syncthreads();
    if (t < 64) totS[t] = red[0][t]+red[1][t]+red[2][t]+red[3][t];
    __syncthreads();
    if (t < DIM) {
        float mean = totS[t] * (1.f/N_NODES);
        float var  = totS[DIM+t] * (1.f/N_NODES) - mean*mean;
        float sc = gamma[layer*DIM+t] * rsqrtf(var + 1e-5f);
        ss[t] = sc;
        ss[DIM+t] = beta[layer*DIM+t] - mean*sc;
    }
    for (int i = t; i < NSLICE*64; i += 256) part[i] = 0.f;
}

// Global add pool with BN applied: hg[batch[n]] += BN(z[n])
__global__ __launch_bounds__(256) void k_pool(
    const float* __restrict__ z, const float* __restrict__ ss,
    const int* __restrict__ batch, float* __restrict__ hg)
{
    long g = (long)blockIdx.x*256 + threadIdx.x;
    int node = (int)(g >> 5);
    int c = (int)(g & 31);
    int b = batch[node];
    float v = z[(long)node*DIM + c]*ss[c] + ss[DIM+c];
    atomicAdd(&hg[b*DIM + c], v);
}

// xd = ReLU(hg @ w_fcxd + b) -> xc[:, 0:128]
__global__ __launch_bounds__(128) void k_xd(
    const float* __restrict__ hg, const float* __restrict__ w,
    const float* __restrict__ bias, float* __restrict__ xc)
{
    int b = blockIdx.x, n = threadIdx.x;
    __shared__ float hS[DIM];
    if (n < DIM) hS[n] = hg[b*DIM+n];
    __syncthreads();
    float acc = bias[n];
    #pragma unroll
    for (int r=0; r<DIM; ++r) acc += hS[r]*w[r*OUTD+n];
    xc[b*256 + n] = fmaxf(acc, 0.f);
}

// ---------------- protein branch ----------------

__global__ __launch_bounds__(256) void k_cw_transpose(
    const float* __restrict__ cw, float* __restrict__ cwT)
{
    int g = blockIdx.x*256 + threadIdx.x;   // 256000 total
    int i = g >> 8;
    int j = g & 255;
    int o = j >> 3, k = j & 7;
    cwT[g] = cw[o*(PLEN*KS) + i*KS + k];
}

__global__ __launch_bounds__(256) void k_conv(
    const int* __restrict__ target, const float* __restrict__ emb,
    const float* __restrict__ cwT, const float* __restrict__ conv_b,
    float* __restrict__ c)
{
    __shared__ float embS[VOCAB*EMBD + 8];
    __shared__ float Gs[VOCAB*256];
    __shared__ int   sortedS[PLEN];
    __shared__ int   cntS[VOCAB];
    __shared__ int   segS[VOCAB+1];
    __shared__ int   curS[VOCAB];
    __shared__ float cbS[NF];
    int b = blockIdx.x, j = threadIdx.x;
    for (int i=j; i<VOCAB*EMBD; i+=256) embS[i] = emb[i];
    if (j < VOCAB) cntS[j] = 0;
    if (j < NF) cbS[j] = conv_b[j];
    __syncthreads();
    int tloc[4];
    #pragma unroll
    for (int q=0; q<4; ++q) {
        int i = j + q*256;
        if (i < PLEN) {
            tloc[q] = target[b*PLEN+i];
            atomicAdd(&cntS[tloc[q]], 1);
        } else tloc[q] = -1;
    }
    __syncthreads();
    if (j == 0) {
        int run = 0;
        for (int v=0; v<VOCAB; ++v) { segS[v]=run; run += cntS[v]; }
        segS[VOCAB] = run;
    }
    __syncthreads();
    if (j < VOCAB) curS[j] = segS[j];
    __syncthreads();
    #pragma unroll
    for (int q=0; q<4; ++q) {
        int i = j + q*256;
        if (i < PLEN) {
            int pos = atomicAdd(&curS[tloc[q]], 1);
            sortedS[pos] = i;
        }
    }
    __syncthreads();
    for (int v=0; v<VOCAB; ++v) {
        int s = segS[v], e2 = segS[v+1];
        float acc = 0.f;
        int p = s;
        for (; p+4 <= e2; p += 4) {
            int i0=sortedS[p], i1=sortedS[p+1], i2=sortedS[p+2], i3=sortedS[p+3];
            acc += cwT[i0*256+j] + cwT[i1*256+j] + cwT[i2*256+j] + cwT[i3*256+j];
        }
        for (; p<e2; ++p) acc += cwT[sortedS[p]*256+j];
        Gs[v*256+j] = acc;
    }
    __syncthreads();
    int o = j >> 3, pg = j & 7;
    int t0 = pg*16;
    int tcnt = (t0+16 <= CLEN) ? 16 : (CLEN - t0);   // 16 or 9
    float out[16];
    #pragma unroll
    for (int q=0; q<16; ++q) out[q] = cbS[o];
    for (int v=0; v<VOCAB; ++v) {
        float g[KS];
        #pragma unroll
        for (int k=0; k<KS; ++k) g[k] = Gs[v*256 + o*KS + k];
        float e[23];
        const float* ev = &embS[v*EMBD + t0];
        #pragma unroll
        for (int m=0; m<23; ++m) e[m] = ev[m];
        #pragma unroll
        for (int q=0; q<16; ++q) {
            float s = 0.f;
            #pragma unroll
            for (int k=0; k<KS; ++k) s += e[q+k]*g[k];
            out[q] += s;
        }
    }
    __syncthreads();
    float* stage = Gs;
    for (int q=0; q<tcnt; ++q) stage[o*CLEN + t0 + q] = out[q];
    __syncthreads();
    for (int idx=j; idx<FCX; idx+=256)
        c[(long)b*FCX + idx] = stage[idx];
}

// xt: [1024 x 3872] @ [3872 x 128] tiled GEMM with 8-way K-split.
// grid (32, 8); block 256; 32 graphs x 128 cols per block; BK=44, 11 chunks.
#define XT_KSL 484
#define XT_BK  44
__global__ __launch_bounds__(256) void k_xt(
    const float* __restrict__ c, const float* __restrict__ w,
    const float* __restrict__ bias, float* __restrict__ xc)
{
    __shared__ float cS[32][XT_BK];
    __shared__ float wS[XT_BK][128];
    int b0 = blockIdx.x * 32;
    int ks0 = blockIdx.y * XT_KSL;
    int tid = threadIdx.x;
    int cg = tid >> 5;          // graph group 0..7
    int co = tid & 31;          // col group 0..31
    float acc[4][4];
    #pragma unroll
    for (int i2=0;i2<4;++i2)
      #pragma unroll
      for (int j2=0;j2<4;++j2) acc[i2][j2]=0.f;
    for (int ch=0; ch<11; ++ch) {
        int k0 = ks0 + ch*XT_BK;
        for (int idx=tid; idx<32*XT_BK; idx+=256) {
            int g = idx / XT_BK, kk = idx - g*XT_BK;
            cS[g][kk] = c[(long)(b0+g)*FCX + k0 + kk];
        }
        for (int idx=tid; idx<XT_BK*128; idx+=256) {
            int kk = idx >> 7, n = idx & 127;
            wS[kk][n] = w[(long)(k0+kk)*OUTD + n];
        }
        __syncthreads();
        #pragma unroll 4
        for (int kk=0; kk<XT_BK; ++kk) {
            float cv[4], wv[4];
            #pragma unroll
            for (int q=0;q<4;++q) cv[q] = cS[cg*4+q][kk];
            #pragma unroll
            for (int p=0;p<4;++p) wv[p] = wS[kk][co*4+p];
            #pragma unroll
            for (int q=0;q<4;++q)
              #pragma unroll
              for (int p=0;p<4;++p) acc[q][p] += cv[q]*wv[p];
        }
        __syncthreads();
    }
    #pragma unroll
    for (int q=0;q<4;++q) {
        int g = b0 + cg*4 + q;
        #pragma unroll
        for (int p=0;p<4;++p) {
            int n = co*4 + p;
            float v = acc[q][p];
            if (blockIdx.y == 0) v += bias[n];
            atomicAdd(&xc[g*256 + 128 + n], v);
        }
    }
}

// ---------------- joint head ----------------

__global__ __launch_bounds__(256) void k_fc1(
    const float* __restrict__ xc, const float* __restrict__ w,
    const float* __restrict__ bias, float* __restrict__ y)
{
    __shared__ float xS[4][256];
    int b0 = blockIdx.x*4, n = threadIdx.x;
    #pragma unroll
    for (int q=0; q<4; ++q) xS[q][n] = xc[(b0+q)*256 + n];
    __syncthreads();
    float acc[4][4];
    #pragma unroll
    for (int m=0; m<4; ++m) {
        float bv = bias[m*256+n];
        #pragma unroll
        for (int q=0; q<4; ++q) acc[q][m] = bv;
    }
    for (int r=0; r<256; ++r) {
        float x0=xS[0][r], x1=xS[1][r], x2=xS[2][r], x3=xS[3][r];
        #pragma unroll
        for (int m=0; m<4; ++m) {
            float wv = w[r*1024 + m*256 + n];
            acc[0][m]+=x0*wv; acc[1][m]+=x1*wv; acc[2][m]+=x2*wv; acc[3][m]+=x3*wv;
        }
    }
    #pragma unroll
    for (int q=0; q<4; ++q)
        #pragma unroll
        for (int m=0; m<4; ++m)
            y[(b0+q)*1024 + m*256 + n] = fmaxf(acc[q][m], 0.f);
}

__global__ __launch_bounds__(256) void k_fc2(
    const float* __restrict__ y, const float* __restrict__ w,
    const float* __restrict__ bias, float* __restrict__ y2)
{
    __shared__ float xS[4][1024];
    int b0 = blockIdx.x*4, n = threadIdx.x;
    #pragma unroll
    for (int q=0; q<4; ++q)
        for (int i=n; i<1024; i+=256) xS[q][i] = y[(b0+q)*1024 + i];
    __syncthreads();
    float acc[4];
    #pragma unroll
    for (int q=0; q<4; ++q) acc[q] = bias[n];
    for (int r=0; r<1024; ++r) {
        float wv = w[r*256 + n];
        #pragma unroll
        for (int q=0; q<4; ++q) acc[q] += xS[q][r]*wv;
    }
    #pragma unroll
    for (int q=0; q<4; ++q) y2[(b0+q)*256 + n] = fmaxf(acc[q], 0.f);
}

__global__ __launch_bounds__(256) void k_out(
    const float* __restrict__ y2, const float* __restrict__ w,
    const float* __restrict__ bias, float* __restrict__ out)
{
    int b = blockIdx.x, n = threadIdx.x;
    float v = y2[b*256 + n] * w[n];
    #pragma unroll
    for (int off=32; off; off>>=1) v += __shfl_down(v, off, 64);
    __shared__ float red[4];
    if ((n & 63) == 0) red[n >> 6] = v;
    __syncthreads();
    if (n == 0) out[b] = red[0]+red[1]+red[2]+red[3] + bias[0];
}

// ---------------- launch ----------------

extern "C" void kernel_launch(void* const* d_in, const int* in_sizes, int n_in,
                              void* d_out, int out_size, void* d_ws, size_t ws_size,
                              hipStream_t stream) {
    const float* x      = (const float*)d_in[0];
    const int*   ei     = (const int*)  d_in[1];
    const int*   batch  = (const int*)  d_in[2];
    const int*   target = (const int*)  d_in[3];
    const float* w1a    = (const float*)d_in[4];
    const float* b1a    = (const float*)d_in[5];
    const float* w1b    = (const float*)d_in[6];
    const float* b1b    = (const float*)d_in[7];
    const float* wa     = (const float*)d_in[8];
    const float* ba     = (const float*)d_in[9];
    const float* wb     = (const float*)d_in[10];
    const float* bb     = (const float*)d_in[11];
    const float* gamma  = (const float*)d_in[12];
    const float* beta   = (const float*)d_in[13];
    const float* w_fcxd = (const float*)d_in[14];
    const float* b_fcxd = (const float*)d_in[15];
    const float* emb    = (const float*)d_in[16];
    const float* conv_w = (const float*)d_in[17];
    const float* conv_b = (const float*)d_in[18];
    const float* w_fcxt = (const float*)d_in[19];
    const float* b_fcxt = (const float*)d_in[20];
    const float* w_fc1  = (const float*)d_in[21];
    const float* b_fc1  = (const float*)d_in[22];
    const float* w_fc2  = (const float*)d_in[23];
    const float* b_fc2  = (const float*)d_in[24];
    const float* w_out  = (const float*)d_in[25];
    const float* b_out  = (const float*)d_in[26];

    float* ws     = (float*)d_ws;
    float* t_buf  = ws;                                   // 2M
    float* z      = t_buf + (size_t)N_NODES*DIM;          // 2M
    int*   csr    = (int*)(z + (size_t)N_NODES*DIM);      // 2M
    int*   rowptr = csr + N_EDGES;                        // N+1 (padded)
    int*   cursor = rowptr + (N_NODES + 8);               // N
    int*   bsum   = cursor + N_NODES;                     // 256
    int*   boffs  = bsum + 256;                           // 256
    float* ss     = (float*)(boffs + 256);                // 64
    float* hg     = ss + 64;                              // 32768
    float* cwT    = hg + (size_t)NB*DIM;                  // 256000
    float* cbuf   = cwT + 256000;                         // 3964928
    float* xc     = cbuf + (size_t)NB*FCX;                // 262144
    float* y1     = xc + (size_t)NB*256;                  // 1048576
    float* y2     = y1 + (size_t)NB*1024;                 // 262144
    float* part   = y2 + (size_t)NB*256;                  // NSLICE*64 = 16384

    // ---- CSR build (cursor doubles as deg buffer) ----
    hipMemsetAsync(cursor, 0, N_NODES*sizeof(int), stream);
    k_deg<<<N_EDGES/256, 256, 0, stream>>>(ei, cursor);
    k_scan1<<<N_NODES/256, 256, 0, stream>>>(cursor, rowptr, bsum);
    k_scan2<<<1, 256, 0, stream>>>(bsum, boffs);
    k_scan3<<<N_NODES/256, 256, 0, stream>>>(rowptr, boffs, cursor);
    k_fill<<<N_EDGES/256, 256, 0, stream>>>(ei, cursor, csr);

    // ---- protein branch ----
    hipMemsetAsync(xc, 0, (size_t)NB*256*sizeof(float), stream);
    k_cw_transpose<<<1000, 256, 0, stream>>>(conv_w, cwT);
    k_conv<<<NB, 256, 0, stream>>>(target, emb, cwT, conv_b, cbuf);
    k_xt<<<dim3(32, 8), 256, 0, stream>>>(cbuf, w_fcxt, b_fcxt, xc);

    // ---- GIN layers ----
    hipMemsetAsync(part, 0, NSLICE*64*sizeof(float), stream);
    for (int l=0; l<5; ++l) {
        if (l == 0)
            k_l1_transform<<<N_NODES/256, 256, 0, stream>>>(x, w1a, t_buf);
        else
            k_transform<<<N_NODES/256, 256, 0, stream>>>(z, ss, wa + (size_t)(l-1)*DIM*DIM, t_buf);
        const float* bi = (l==0) ? b1a : ba + (size_t)(l-1)*DIM;
        const float* wo = (l==0) ? w1b : wb + (size_t)(l-1)*DIM*DIM;
        const float* bo = (l==0) ? b1b : bb + (size_t)(l-1)*DIM;
        k_gather_mlp<<<N_NODES/8, 256, 0, stream>>>(rowptr, csr, t_buf, bi, wo, bo, z, part);
        k_scaleshift<<<1, 256, 0, stream>>>(part, gamma, beta, l, ss);
    }

    // ---- pool + drug head ----
    hipMemsetAsync(hg, 0, (size_t)NB*DIM*sizeof(float), stream);
    k_pool<<<(N_NODES*32)/256, 256, 0, stream>>>(z, ss, batch, hg);
    k_xd<<<NB, 128, 0, stream>>>(hg, w_fcxd, b_fcxd, xc);

    // ---- joint head ----
    k_fc1<<<NB/4, 256, 0, stream>>>(xc, w_fc1, b_fc1, y1);
    k_fc2<<<NB/4, 256, 0, stream>>>(y1, w_fc2, b_fc2, y2);
    k_out<<<NB, 256, 0, stream>>>(y2, w_out, b_out, (float*)d_out);
}